// Round 3
// baseline (254.851 us; speedup 1.0000x reference)
//
#include <hip/hip_runtime.h>
#include <math.h>

#define B_SZ 24
#define D_EMBD 512
#define N_CLS 10000
#define CC 256
#define HH 196

#define NPAIR 276
#define NARC 40
#define NGRAM 36

#define S_SCALE 64.0f
#define COS_M 0.9004471023526769f
#define SIN_M 0.43496553411123023f
#define TH_C (-0.9004471023526769f)
#define MM_C 0.19573449035005357f
// base-2 scaled Sinkhorn units: Ceps2 = C * log2(e)/eps
#define KSC 14.4269504088896f          /* 10*log2(e) */
#define C2E 0.0693147180559945f        /* eps*ln2 */

typedef short bfrag8 __attribute__((ext_vector_type(8)));
typedef float facc4 __attribute__((ext_vector_type(4)));

#if __has_builtin(__builtin_amdgcn_exp2f)
#define EXP2F(x) __builtin_amdgcn_exp2f(x)
#else
#define EXP2F(x) exp2f(x)
#endif
#if __has_builtin(__builtin_amdgcn_logf)
#define LOG2F(x) __builtin_amdgcn_logf(x)
#else
#define LOG2F(x) __log2f(x)
#endif

// ================= Launch 1: fused pairs (Sinkhorn) + arcface + emb gram =================
// blocks 0..275          : one (a<b) Sinkhorn pair each (16 waves, 4x4 wave grid)
// blocks 276..315 (40)   : arcface, 256 cols each, kc=t&3 k-quarter per thread
// blocks 316..351 (36)   : 24x24 emb-cosine gram, one pair per wave; first zeros Dmat diag
//
// NOTE (R2 post-mortem): pair path is at EXACTLY the 128 reg/thread unified
// VGPR+AGPR budget (64 E/temps + 64 acc) at 1024 thr. Any structure that keeps
// staging temps live across the MFMA loop (e.g. LDS double-buffering) spills
// ~550 B/thread to scratch (+250 MB HBM traffic, 1.6x slower). Keep the
// single-buffer 2-barrier GEMM.
__global__ __launch_bounds__(1024) void k_fused(const float* __restrict__ emb,
        const float* __restrict__ conv, const float* __restrict__ kern,
        const int* __restrict__ label, float* __restrict__ dists,
        float* __restrict__ Dmat, float* __restrict__ out) {
    const int t = threadIdx.x;
    const int bid = blockIdx.x;

    __shared__ __align__(16) char smem[65536];

    if (bid >= NPAIR) {
        const int sb = bid - NPAIR;
        if (sb >= NARC) {
            // ---- emb gram path (no barriers, no LDS) ----
            const int gid = sb - NARC;
            int l = t & 63, w16 = t >> 6;
            if (gid == 0 && t < B_SZ) Dmat[t * B_SZ + t] = 0.f;
            int pid = gid * 16 + w16;
            if (pid >= B_SZ * B_SZ) return;
            int i = pid / B_SZ, j = pid - (pid / B_SZ) * B_SZ;
            float sij = 0.f, sii = 0.f, sjj = 0.f;
            #pragma unroll
            for (int u = 0; u < 8; ++u) {
                float vi = emb[i*D_EMBD + u*64 + l];
                float vj = emb[j*D_EMBD + u*64 + l];
                sij = fmaf(vi, vj, sij); sii = fmaf(vi, vi, sii); sjj = fmaf(vj, vj, sjj);
            }
            #pragma unroll
            for (int o = 1; o < 64; o <<= 1) {
                sij += __shfl_xor(sij, o, 64);
                sii += __shfl_xor(sii, o, 64);
                sjj += __shfl_xor(sjj, o, 64);
            }
            if (l == 0) dists[pid] = sij * rsqrtf(sii * sjj);
            return;
        }

        // ---- arcface path: 256 cols/block, self-normalizing, reg-only chunk reduce ----
        float* es = (float*)smem;                 // 12288 floats (48 KB)
        float* inv_s = es + B_SZ * D_EMBD;        // 24
        int* lab_s = (int*)(inv_s + B_SZ);        // 24

        {
            const float4* s4 = (const float4*)emb;
            float4* d4 = (float4*)es;
            #pragma unroll
            for (int i = 0; i < 3; ++i) d4[i*1024 + t] = s4[i*1024 + t];
        }
        if (t < B_SZ) lab_s[t] = label[t];
        __syncthreads();
        {   // row norms of emb (16 waves)
            int l = t & 63, w = t >> 6;
            for (int r = w; r < B_SZ; r += 16) {
                float s = 0.f;
                #pragma unroll
                for (int u = 0; u < 8; ++u) { float v = es[r*D_EMBD + u*64 + l]; s = fmaf(v, v, s); }
                #pragma unroll
                for (int o = 1; o < 64; o <<= 1) s += __shfl_xor(s, o, 64);
                if (l == 0) inv_s[r] = rsqrtf(s);
            }
        }
        __syncthreads();

        const int cc = t >> 2, kc = t & 3;        // 256 cols, 4 k-quarters of 128
        const int col = sb * 256 + cc;
        const int cL = col < N_CLS ? col : N_CLS - 1;
        float acc[B_SZ];
        #pragma unroll
        for (int r = 0; r < B_SZ; ++r) acc[r] = 0.f;
        float cn = 0.f;
        const int kb0 = kc << 7;
        for (int u = 0; u < 32; ++u) {
            // per-kc rotation of the k-walk keeps the 4 kc-groups' broadcast
            // float4 LDS reads on disjoint banks
            const int um = (u + kc) & 31;
            const int kb = kb0 + (um << 2);
            float kv0 = kern[(kb+0)*N_CLS + cL];
            float kv1 = kern[(kb+1)*N_CLS + cL];
            float kv2 = kern[(kb+2)*N_CLS + cL];
            float kv3 = kern[(kb+3)*N_CLS + cL];
            cn = fmaf(kv0,kv0,cn); cn = fmaf(kv1,kv1,cn);
            cn = fmaf(kv2,kv2,cn); cn = fmaf(kv3,kv3,cn);
            #pragma unroll
            for (int r = 0; r < B_SZ; ++r) {
                const float4 e = *(const float4*)&es[r*D_EMBD + kb];
                acc[r] = fmaf(e.x, kv0, acc[r]);
                acc[r] = fmaf(e.y, kv1, acc[r]);
                acc[r] = fmaf(e.z, kv2, acc[r]);
                acc[r] = fmaf(e.w, kv3, acc[r]);
            }
        }
        cn += __shfl_xor(cn, 1, 64); cn += __shfl_xor(cn, 2, 64);
        #pragma unroll
        for (int r = 0; r < B_SZ; ++r) {
            acc[r] += __shfl_xor(acc[r], 1, 64);
            acc[r] += __shfl_xor(acc[r], 2, 64);
        }
        if (kc == 0 && col < N_CLS) {
            const float invk = rsqrtf(cn);
            #pragma unroll
            for (int r = 0; r < B_SZ; ++r) {
                float cosv = fminf(fmaxf(acc[r] * inv_s[r] * invk, -1.f), 1.f);
                float oc = cosv * S_SCALE;
                float af = oc;
                if (lab_s[r] == col) {
                    float tl = cosv;
                    float sint = sqrtf(fmaxf(1.f - tl*tl, 0.f));
                    float ctm = tl*COS_M - sint*SIN_M;
                    float ftl = (tl > TH_C) ? ctm : (tl - MM_C);
                    af = ftl * S_SCALE;
                }
                out[r*N_CLS + col] = af;
                out[240001 + r*N_CLS + col] = oc;
            }
        }
        return;
    }

    // ======================= Sinkhorn pair path =======================
    // GEMM overlay: 4 staging buffers [256 rows][32 k] bf16 (16 KB each)
    unsigned short* Ah = (unsigned short*)smem;
    unsigned short* Al = Ah + 8192;
    unsigned short* Bh = Al + 8192;
    unsigned short* Bl = Bh + 8192;
    // Sinkhorn overlay (used strictly after GEMM's last fragment-read barrier)
    float* rowred = (float*)smem;        // [4][256]
    float* colred = rowred + 1024;       // [4][256]
    float* rm_l   = colred + 1024;       // [256]
    float* z_l    = rm_l + 256;          // [256]
    float* g_l    = z_l + 256;           // [256]
    float* q_l    = g_l + 256;           // [256]  2^(z - MS), built in phase B
    float* na_s   = q_l + 256;           // [256]
    float* nb_s   = na_s + 256;          // [256]
    float* wredF  = nb_s + 256;          // [4]
    float* wredG  = wredF + 4;           // [4]
    float* wredD  = wredG + 4;           // [16]

    const int w = t >> 6;
    const int wr = w >> 2, wc = w & 3;
    const int q = (t >> 4) & 3, c0 = t & 15;
    const int R0 = wr * 64, C0 = wc * 64;

    // pair index -> (a, b), a < b
    int rem = bid, a = 0;
    while (rem >= 23 - a) { rem -= 23 - a; ++a; }
    int b = a + 1 + rem;
    const float* xa = conv + a*CC*HH;
    const float* xb = conv + b*CC*HH;

    const int sn = t >> 2;               // staging row 0..255
    const int sch = t & 3;               // staging 8-k chunk

    facc4 acc[4][4];
    #pragma unroll
    for (int i = 0; i < 4; ++i)
        #pragma unroll
        for (int j = 0; j < 4; ++j) acc[i][j] = (facc4){0.f, 0.f, 0.f, 0.f};

    float pa = 0.f, pb = 0.f;            // inline point-norm partials

    // ---- GEMM: G = Xa . Xb^T, K padded 196 -> 224, 7 K-steps of 32 ----
    // Single-buffer, 2 barriers per k-step (fits the 128 reg/thread budget).
    for (int ks = 0; ks < 224; ks += 32) {
        __syncthreads();
        #pragma unroll
        for (int p = 0; p < 2; ++p) {
            const int k0 = ks + sch*8;
            const float* src = (p ? xb : xa) + sn*HH + k0;
            float v[8];
            if (k0 + 8 <= HH) {
                const float4* s4 = (const float4*)src;
                float4 u0 = s4[0], u1 = s4[1];
                v[0]=u0.x; v[1]=u0.y; v[2]=u0.z; v[3]=u0.w;
                v[4]=u1.x; v[5]=u1.y; v[6]=u1.z; v[7]=u1.w;
            } else {
                #pragma unroll
                for (int j = 0; j < 8; ++j) v[j] = (k0 + j < HH) ? src[j] : 0.f;
            }
            // truncation hi/lo split + v_perm packing (exact h, l = v - h)
            float ps = 0.f;
            unsigned hw[4], lw[4];
            #pragma unroll
            for (int j = 0; j < 4; ++j) {
                float v0 = v[2*j], v1 = v[2*j+1];
                ps = fmaf(v0, v0, ps); ps = fmaf(v1, v1, ps);
                unsigned u0 = __float_as_uint(v0), u1 = __float_as_uint(v1);
                float h0 = __uint_as_float(u0 & 0xFFFF0000u);
                float h1 = __uint_as_float(u1 & 0xFFFF0000u);
                unsigned l0 = __float_as_uint(v0 - h0);
                unsigned l1 = __float_as_uint(v1 - h1);
                hw[j] = __builtin_amdgcn_perm(u1, u0, 0x07060302u);  // [bf16(v1):bf16(v0)]
                lw[j] = __builtin_amdgcn_perm(l1, l0, 0x07060302u);
            }
            if (p) pb += ps; else pa += ps;
            unsigned short* dh = (p ? Bh : Ah) + sn*32 + sch*8;
            unsigned short* dl = (p ? Bl : Al) + sn*32 + sch*8;
            *(uint4*)dh = (uint4){hw[0], hw[1], hw[2], hw[3]};
            *(uint4*)dl = (uint4){lw[0], lw[1], lw[2], lw[3]};
        }
        __syncthreads();
        bfrag8 bh4[4], bl4[4];
        #pragma unroll
        for (int tj = 0; tj < 4; ++tj) {
            int col = C0 + tj*16 + c0;
            bh4[tj] = *(const bfrag8*)(Bh + col*32 + q*8);
            bl4[tj] = *(const bfrag8*)(Bl + col*32 + q*8);
        }
        #pragma unroll
        for (int ti = 0; ti < 4; ++ti) {
            int row = R0 + ti*16 + c0;
            bfrag8 ah = *(const bfrag8*)(Ah + row*32 + q*8);
            bfrag8 al = *(const bfrag8*)(Al + row*32 + q*8);
            #pragma unroll
            for (int tj = 0; tj < 4; ++tj) {
                acc[ti][tj] = __builtin_amdgcn_mfma_f32_16x16x32_bf16(ah, bh4[tj], acc[ti][tj], 0, 0, 0);
                acc[ti][tj] = __builtin_amdgcn_mfma_f32_16x16x32_bf16(ah, bl4[tj], acc[ti][tj], 0, 0, 0);
                acc[ti][tj] = __builtin_amdgcn_mfma_f32_16x16x32_bf16(al, bh4[tj], acc[ti][tj], 0, 0, 0);
            }
        }
    }
    __syncthreads();   // GEMM frag reads done; LDS reused for Sinkhorn

    // point norms: quad-reduce (4 threads per row, lane-adjacent)
    pa += __shfl_xor(pa, 1, 64); pa += __shfl_xor(pa, 2, 64);
    pb += __shfl_xor(pb, 1, 64); pb += __shfl_xor(pb, 2, 64);
    if (sch == 0) { na_s[sn] = pa; nb_s[sn] = pb; }
    if (t < 256) g_l[t] = 0.f;
    if (t < 4) { wredG[t] = 0.f; wredF[t] = 8.f; }   // MS0 = 8 bounds iter-0 z
    __syncthreads();

    // C/D layout (16x16x32): row = R0 + ti*16 + q*4 + r, col = C0 + tj*16 + c0
    facc4 E[4][4];                        // first Ceps2, then 2^(rm - Ceps2)
    {
        float nbv[4];
        #pragma unroll
        for (int tj = 0; tj < 4; ++tj) nbv[tj] = nb_s[C0 + tj*16 + c0];
        #pragma unroll
        for (int ti = 0; ti < 4; ++ti) {
            facc4 nav = *(const facc4*)&na_s[R0 + ti*16 + q*4];
            #pragma unroll
            for (int tj = 0; tj < 4; ++tj) {
                #pragma unroll
                for (int r = 0; r < 4; ++r) {
                    float d2 = fmaxf(nav[r] + nbv[tj] - 2.f*acc[ti][tj][r], 0.f);
                    E[ti][tj][r] = KSC * sqrtf(d2 + 1e-12f);
                }
            }
        }
    }

    // tournament target indices (verified in R2)
    const int istar = ((c0&1)<<3) | ((c0&2)<<1) | ((c0&4)>>1) | ((c0&8)>>3);
    const int rowstar = R0 + (istar>>2)*16 + q*4 + (istar&3);
    const int tjstar = ((q&1)<<1) | (q>>1);
    const int colstar = C0 + tjstar*16 + c0;

    // ---- row mins of Ceps2 ----
    {
        float v16[16];
        #pragma unroll
        for (int ti = 0; ti < 4; ++ti)
            #pragma unroll
            for (int r = 0; r < 4; ++r)
                v16[ti*4+r] = fminf(fminf(E[ti][0][r], E[ti][1][r]),
                                    fminf(E[ti][2][r], E[ti][3][r]));
        #pragma unroll
        for (int p = 0; p < 4; ++p) {
            const int m = 1 << p, hsz = 8 >> p;
            const bool hi = (c0 >> p) & 1;
            #pragma unroll
            for (int j = 0; j < hsz; ++j) {
                float mine = hi ? v16[j+hsz] : v16[j];
                float send = hi ? v16[j] : v16[j+hsz];
                v16[j] = fminf(mine, __shfl_xor(send, m, 64));
            }
        }
        rowred[wc*256 + rowstar] = v16[0];
    }
    __syncthreads();
    if (t < 256)
        rm_l[t] = fminf(fminf(rowred[t], rowred[256+t]), fminf(rowred[512+t], rowred[768+t]));
    __syncthreads();

    // E := 2^(rm_r - Ceps2)
    #pragma unroll
    for (int ti = 0; ti < 4; ++ti) {
        facc4 rmv = *(const facc4*)&rm_l[R0 + ti*16 + q*4];
        #pragma unroll
        for (int tj = 0; tj < 4; ++tj)
            #pragma unroll
            for (int r = 0; r < 4; ++r)
                E[ti][tj][r] = EXP2F(rmv[r] - E[ti][tj][r]);
    }

    // ---- 6 Sinkhorn iterations ----
    // Shifts are exact renormalizers; MS (z-shift) is the PREVIOUS iteration's
    // max-z (stale by one iteration, init 8) so phase B precomputes
    // q_l = 2^(z - MS) and phase C needs no exp2 at all.
    #pragma unroll 1
    for (int it = 0; it < 6; ++it) {
        float Gmax = fmaxf(fmaxf(wredG[0], wredG[1]), fmaxf(wredG[2], wredG[3]));
        float MS   = fmaxf(fmaxf(wredF[0], wredF[1]), fmaxf(wredF[2], wredF[3]));
        // phase A: row sums  S_r = sum_c E * 2^(G_c - Gmax)
        float P4[4];
        #pragma unroll
        for (int tj = 0; tj < 4; ++tj) P4[tj] = EXP2F(g_l[C0 + tj*16 + c0] - Gmax);
        float v16[16];
        #pragma unroll
        for (int ti = 0; ti < 4; ++ti)
            #pragma unroll
            for (int r = 0; r < 4; ++r) {
                float s = 0.f;
                #pragma unroll
                for (int tj = 0; tj < 4; ++tj) s = fmaf(E[ti][tj][r], P4[tj], s);
                v16[ti*4+r] = s;
            }
        #pragma unroll
        for (int p = 0; p < 4; ++p) {
            const int m = 1 << p, hsz = 8 >> p;
            const bool hi = (c0 >> p) & 1;
            #pragma unroll
            for (int j = 0; j < hsz; ++j) {
                float mine = hi ? v16[j+hsz] : v16[j];
                float send = hi ? v16[j] : v16[j+hsz];
                v16[j] = mine + __shfl_xor(send, m, 64);
            }
        }
        rowred[wc*256 + rowstar] = v16[0];
        __syncthreads();
        // phase B: z_r = 8 - Gmax - log2(S_r); q_l = 2^(z - MS); wave-max z -> wredF
        if (t < 256) {
            float s = rowred[t] + rowred[256+t] + rowred[512+t] + rowred[768+t];
            float z = 8.f - Gmax - LOG2F(s);
            z_l[t] = z;
            q_l[t] = EXP2F(z - MS);
            float m = z;
            #pragma unroll
            for (int o = 1; o < 64; o <<= 1) m = fmaxf(m, __shfl_xor(m, o, 64));
            if ((t & 63) == 0) wredF[t >> 6] = m;
        }
        __syncthreads();
        // phase C: col sums  S_c = sum_r E * q_r  (q precomputed, no exp2)
        float Q[16];
        #pragma unroll
        for (int ti = 0; ti < 4; ++ti) {
            facc4 qv = *(const facc4*)&q_l[R0 + ti*16 + q*4];
            #pragma unroll
            for (int r = 0; r < 4; ++r) Q[ti*4+r] = qv[r];
        }
        float w4[4];
        #pragma unroll
        for (int tj = 0; tj < 4; ++tj) {
            float s = 0.f;
            #pragma unroll
            for (int ti = 0; ti < 4; ++ti)
                #pragma unroll
                for (int r = 0; r < 4; ++r) s = fmaf(E[ti][tj][r], Q[ti*4+r], s);
            w4[tj] = s;
        }
        #pragma unroll
        for (int p = 0; p < 2; ++p) {
            const int m = 16 << p, hsz = 2 >> p;
            const bool hi = (q >> p) & 1;
            #pragma unroll
            for (int j = 0; j < hsz; ++j) {
                float mine = hi ? w4[j+hsz] : w4[j];
                float send = hi ? w4[j] : w4[j+hsz];
                w4[j] = mine + __shfl_xor(send, m, 64);
            }
        }
        colred[wr*256 + colstar] = w4[0];
        __syncthreads();
        // phase D: G_c = 8 - MS - log2(S_c); wave-max -> wredG
        if (t < 256) {
            float s = colred[t] + colred[256+t] + colred[512+t] + colred[768+t];
            float G = 8.f - MS - LOG2F(s);
            g_l[t] = G;
            float m = G;
            #pragma unroll
            for (int o = 1; o < 64; o <<= 1) m = fmaxf(m, __shfl_xor(m, o, 64));
            if ((t & 63) == 0) wredG[t >> 6] = m;
        }
        __syncthreads();
    }

    // ---- D = sum(T*C): T = 2^(z_r-8)*2^(G_c-8)*E, C-weight = rm_r - log2 E ----
    {
        float gc[4];
        #pragma unroll
        for (int tj = 0; tj < 4; ++tj) gc[tj] = EXP2F(g_l[C0 + tj*16 + c0] - 8.f);
        float d = 0.f;
        #pragma unroll
        for (int ti = 0; ti < 4; ++ti) {
            facc4 zv = *(const facc4*)&z_l[R0 + ti*16 + q*4];
            facc4 rmv = *(const facc4*)&rm_l[R0 + ti*16 + q*4];
            float fr[4];
            #pragma unroll
            for (int r = 0; r < 4; ++r) fr[r] = EXP2F(zv[r] - 8.f);
            #pragma unroll
            for (int tj = 0; tj < 4; ++tj) {
                #pragma unroll
                for (int r = 0; r < 4; ++r) {
                    float e = fmaxf(E[ti][tj][r], 1e-45f);
                    float lE = LOG2F(e);
                    d = fmaf(e * (fr[r] * gc[tj]), rmv[r] - lE, d);
                }
            }
        }
        d *= C2E;
        #pragma unroll
        for (int o = 1; o < 64; o <<= 1) d += __shfl_xor(d, o, 64);
        if ((t & 63) == 0) wredD[w] = d;
        __syncthreads();
        if (t == 0) {
            float s = 0.f;
            #pragma unroll
            for (int i = 0; i < 16; ++i) s += wredD[i];
            Dmat[a*B_SZ + b] = s;
            Dmat[b*B_SZ + a] = s;
        }
    }
}

// ================= Launch 2: final triplet scan + scalar outputs (1 block) =================
__global__ __launch_bounds__(256) void k_fin(const int* __restrict__ label,
        const float* __restrict__ dists, const float* __restrict__ Dmat,
        float* __restrict__ out) {
    const int t = threadIdx.x;
    __shared__ float ds[576], Dm[576];
    __shared__ int lab[B_SZ];
    __shared__ float wls[4]; __shared__ int wnp[4], wot[4];
    for (int i = t; i < 576; i += 256) { ds[i] = dists[i]; Dm[i] = Dmat[i]; }
    if (t < B_SZ) lab[t] = label[t];
    __syncthreads();
    int np = 0, ot = 0; float wsum = 0.f;
    for (int idx = t; idx < 24*24*24; idx += 256) {
        int a2 = idx / 576;
        int rest = idx - a2*576;
        int p2 = rest / 24;
        int n2 = rest - p2*24;
        int la = lab[a2];
        if (la == lab[p2] && la != lab[n2]) {
            float diff = ds[a2*24 + n2] - ds[a2*24 + p2];
            if (diff > 0.f) {
                ++np;
                float dd = Dm[a2*24 + p2] - Dm[a2*24 + n2];
                if (dd > 0.f) { ++ot; wsum += dd; }
            }
        }
    }
    #pragma unroll
    for (int o = 1; o < 64; o <<= 1) {
        np += __shfl_xor(np, o, 64);
        ot += __shfl_xor(ot, o, 64);
        wsum += __shfl_xor(wsum, o, 64);
    }
    int w = t >> 6;
    if ((t & 63) == 0) { wnp[w] = np; wot[w] = ot; wls[w] = wsum; }
    __syncthreads();
    if (t == 0) {
        int tnp = wnp[0]+wnp[1]+wnp[2]+wnp[3];
        int tot = wot[0]+wot[1]+wot[2]+wot[3];
        float tws = wls[0]+wls[1]+wls[2]+wls[3];
        int den = tot > 1 ? tot : 1;
        float wl = (tws > 0.f) ? tws / (float)den : 0.f;
        out[240000] = wl;
        out[480001] = (float)tnp;
        out[480002] = (float)tot;
    }
}

extern "C" void kernel_launch(void* const* d_in, const int* in_sizes, int n_in,
                              void* d_out, int out_size, void* d_ws, size_t ws_size,
                              hipStream_t stream) {
    (void)in_sizes; (void)n_in; (void)out_size; (void)ws_size;
    const float* emb  = (const float*)d_in[0];
    const float* conv = (const float*)d_in[1];
    const float* kern = (const float*)d_in[2];
    const int*   lab  = (const int*)d_in[3];
    float* out = (float*)d_out;
    float* ws  = (float*)d_ws;
    float* dists = ws;            // 576 floats
    float* Dmat  = ws + 576;      // 576 floats

    k_fused<<<NPAIR + NARC + NGRAM, 1024, 0, stream>>>(emb, conv, kern, lab, dists, Dmat, out);
    k_fin<<<1, 256, 0, stream>>>(lab, dists, Dmat, out);
}

// Round 4
// 248.727 us; speedup vs baseline: 1.0246x; 1.0246x over previous
//
#include <hip/hip_runtime.h>
#include <math.h>

#define B_SZ 24
#define D_EMBD 512
#define N_CLS 10000
#define CC 256
#define HH 196

#define NPAIR 276
#define NARC 40
#define NGRAM 36

#define S_SCALE 64.0f
#define COS_M 0.9004471023526769f
#define SIN_M 0.43496553411123023f
#define TH_C (-0.9004471023526769f)
#define MM_C 0.19573449035005357f
// base-2 scaled Sinkhorn units: Ceps2 = C * log2(e)/eps
#define KSC 14.4269504088896f          /* 10*log2(e) */
#define C2E 0.0693147180559945f        /* eps*ln2 */

typedef short bfrag8 __attribute__((ext_vector_type(8)));
typedef float facc4 __attribute__((ext_vector_type(4)));

#if __has_builtin(__builtin_amdgcn_exp2f)
#define EXP2F(x) __builtin_amdgcn_exp2f(x)
#else
#define EXP2F(x) exp2f(x)
#endif
#if __has_builtin(__builtin_amdgcn_logf)
#define LOG2F(x) __builtin_amdgcn_logf(x)
#else
#define LOG2F(x) __log2f(x)
#endif

// ================= Launch 1: fused pairs (Sinkhorn) + arcface + emb gram =================
// blocks 0..275          : one (a<b) Sinkhorn pair each (16 waves, 4x4 wave grid)
// blocks 276..315 (40)   : arcface, 256 cols each, kc=t&3 k-quarter per thread
// blocks 316..351 (36)   : 24x24 emb-cosine gram, one pair per wave; first zeros Dmat diag
//
// NOTE (R2/R3 post-mortem): pair path sits at the 128 reg/thread unified
// VGPR+AGPR cliff at 1024 thr. The GEMM staging must keep R1's exact
// union-insert live-value structure (shorts inserted into a union, bfrag8
// store). R2/R3's uint4/perm staging variant coincided with ~160 MB of
// excess HBM traffic; this round bisects by keeping the union form.
__global__ __launch_bounds__(1024) void k_fused(const float* __restrict__ emb,
        const float* __restrict__ conv, const float* __restrict__ kern,
        const int* __restrict__ label, float* __restrict__ dists,
        float* __restrict__ Dmat, float* __restrict__ out) {
    const int t = threadIdx.x;
    const int bid = blockIdx.x;

    __shared__ __align__(16) char smem[65536];

    if (bid >= NPAIR) {
        const int sb = bid - NPAIR;
        if (sb >= NARC) {
            // ---- emb gram path (no barriers, no LDS) ----
            const int gid = sb - NARC;
            int l = t & 63, w16 = t >> 6;
            if (gid == 0 && t < B_SZ) Dmat[t * B_SZ + t] = 0.f;
            int pid = gid * 16 + w16;
            if (pid >= B_SZ * B_SZ) return;
            int i = pid / B_SZ, j = pid - (pid / B_SZ) * B_SZ;
            float sij = 0.f, sii = 0.f, sjj = 0.f;
            #pragma unroll
            for (int u = 0; u < 8; ++u) {
                float vi = emb[i*D_EMBD + u*64 + l];
                float vj = emb[j*D_EMBD + u*64 + l];
                sij = fmaf(vi, vj, sij); sii = fmaf(vi, vi, sii); sjj = fmaf(vj, vj, sjj);
            }
            #pragma unroll
            for (int o = 1; o < 64; o <<= 1) {
                sij += __shfl_xor(sij, o, 64);
                sii += __shfl_xor(sii, o, 64);
                sjj += __shfl_xor(sjj, o, 64);
            }
            if (l == 0) dists[pid] = sij * rsqrtf(sii * sjj);
            return;
        }

        // ---- arcface path: 256 cols/block, self-normalizing, reg-only chunk reduce ----
        float* es = (float*)smem;                 // 12288 floats (48 KB)
        float* inv_s = es + B_SZ * D_EMBD;        // 24
        int* lab_s = (int*)(inv_s + B_SZ);        // 24

        {
            const float4* s4 = (const float4*)emb;
            float4* d4 = (float4*)es;
            #pragma unroll
            for (int i = 0; i < 3; ++i) d4[i*1024 + t] = s4[i*1024 + t];
        }
        if (t < B_SZ) lab_s[t] = label[t];
        __syncthreads();
        {   // row norms of emb (16 waves)
            int l = t & 63, w = t >> 6;
            for (int r = w; r < B_SZ; r += 16) {
                float s = 0.f;
                #pragma unroll
                for (int u = 0; u < 8; ++u) { float v = es[r*D_EMBD + u*64 + l]; s = fmaf(v, v, s); }
                #pragma unroll
                for (int o = 1; o < 64; o <<= 1) s += __shfl_xor(s, o, 64);
                if (l == 0) inv_s[r] = rsqrtf(s);
            }
        }
        __syncthreads();

        const int cc = t >> 2, kc = t & 3;        // 256 cols, 4 k-quarters of 128
        const int col = sb * 256 + cc;
        const int cL = col < N_CLS ? col : N_CLS - 1;
        float acc[B_SZ];
        #pragma unroll
        for (int r = 0; r < B_SZ; ++r) acc[r] = 0.f;
        float cn = 0.f;
        const int kb0 = kc << 7;
        for (int u = 0; u < 32; ++u) {
            // per-kc rotation of the k-walk keeps the 4 kc-groups' broadcast
            // float4 LDS reads on disjoint banks
            const int um = (u + kc) & 31;
            const int kb = kb0 + (um << 2);
            float kv0 = kern[(kb+0)*N_CLS + cL];
            float kv1 = kern[(kb+1)*N_CLS + cL];
            float kv2 = kern[(kb+2)*N_CLS + cL];
            float kv3 = kern[(kb+3)*N_CLS + cL];
            cn = fmaf(kv0,kv0,cn); cn = fmaf(kv1,kv1,cn);
            cn = fmaf(kv2,kv2,cn); cn = fmaf(kv3,kv3,cn);
            #pragma unroll
            for (int r = 0; r < B_SZ; ++r) {
                const float4 e = *(const float4*)&es[r*D_EMBD + kb];
                acc[r] = fmaf(e.x, kv0, acc[r]);
                acc[r] = fmaf(e.y, kv1, acc[r]);
                acc[r] = fmaf(e.z, kv2, acc[r]);
                acc[r] = fmaf(e.w, kv3, acc[r]);
            }
        }
        cn += __shfl_xor(cn, 1, 64); cn += __shfl_xor(cn, 2, 64);
        #pragma unroll
        for (int r = 0; r < B_SZ; ++r) {
            acc[r] += __shfl_xor(acc[r], 1, 64);
            acc[r] += __shfl_xor(acc[r], 2, 64);
        }
        if (kc == 0 && col < N_CLS) {
            const float invk = rsqrtf(cn);
            #pragma unroll
            for (int r = 0; r < B_SZ; ++r) {
                float cosv = fminf(fmaxf(acc[r] * inv_s[r] * invk, -1.f), 1.f);
                float oc = cosv * S_SCALE;
                float af = oc;
                if (lab_s[r] == col) {
                    float tl = cosv;
                    float sint = sqrtf(fmaxf(1.f - tl*tl, 0.f));
                    float ctm = tl*COS_M - sint*SIN_M;
                    float ftl = (tl > TH_C) ? ctm : (tl - MM_C);
                    af = ftl * S_SCALE;
                }
                out[r*N_CLS + col] = af;
                out[240001 + r*N_CLS + col] = oc;
            }
        }
        return;
    }

    // ======================= Sinkhorn pair path =======================
    // GEMM overlay: 4 staging buffers [256 rows][32 k] bf16 (16 KB each)
    unsigned short* Ah = (unsigned short*)smem;
    unsigned short* Al = Ah + 8192;
    unsigned short* Bh = Al + 8192;
    unsigned short* Bl = Bh + 8192;
    // Sinkhorn overlay (used strictly after GEMM's last fragment-read barrier)
    float* rowred = (float*)smem;        // [4][256]
    float* colred = rowred + 1024;       // [4][256]
    float* rm_l   = colred + 1024;       // [256]
    float* z_l    = rm_l + 256;          // [256]
    float* g_l    = z_l + 256;           // [256]
    float* q_l    = g_l + 256;           // [256]  2^(z - MS), built in phase B
    float* na_s   = q_l + 256;           // [256]
    float* nb_s   = na_s + 256;          // [256]
    float* wredF  = nb_s + 256;          // [4]
    float* wredG  = wredF + 4;           // [4]
    float* wredD  = wredG + 4;           // [16]

    const int w = t >> 6;
    const int wr = w >> 2, wc = w & 3;
    const int q = (t >> 4) & 3, c0 = t & 15;
    const int R0 = wr * 64, C0 = wc * 64;

    // pair index -> (a, b), a < b
    int rem = bid, a = 0;
    while (rem >= 23 - a) { rem -= 23 - a; ++a; }
    int b = a + 1 + rem;
    const float* xa = conv + a*CC*HH;
    const float* xb = conv + b*CC*HH;

    const int sn = t >> 2;               // staging row 0..255
    const int sch = t & 3;               // staging 8-k chunk

    facc4 acc[4][4];
    #pragma unroll
    for (int i = 0; i < 4; ++i)
        #pragma unroll
        for (int j = 0; j < 4; ++j) acc[i][j] = (facc4){0.f, 0.f, 0.f, 0.f};

    float pa = 0.f, pb = 0.f;            // inline point-norm partials

    // ---- GEMM: G = Xa . Xb^T, K padded 196 -> 224, 7 K-steps of 32 ----
    // Single-buffer, 2 barriers per k-step (fits the 128 reg/thread budget).
    for (int ks = 0; ks < 224; ks += 32) {
        __syncthreads();
        #pragma unroll
        for (int p = 0; p < 2; ++p) {
            const int k0 = ks + sch*8;
            const float* src = (p ? xb : xa) + sn*HH + k0;
            float v[8];
            if (k0 + 8 <= HH) {
                const float4* s4 = (const float4*)src;
                float4 u0 = s4[0], u1 = s4[1];
                v[0]=u0.x; v[1]=u0.y; v[2]=u0.z; v[3]=u0.w;
                v[4]=u1.x; v[5]=u1.y; v[6]=u1.z; v[7]=u1.w;
            } else {
                #pragma unroll
                for (int j = 0; j < 8; ++j) v[j] = (k0 + j < HH) ? src[j] : 0.f;
            }
            // truncation hi/lo split, R1's union-insert structure:
            // hi = trunc-bf16(v) (exact sub), lo = trunc-bf16(v - hi).
            // abs err <= 2^-18*|v| -- same scale as double-RNE, half the ops.
            float ps = 0.f;
            union { unsigned short s[8]; bfrag8 v8; } uh, ul;
            #pragma unroll
            for (int j = 0; j < 8; ++j) {
                float vj = v[j];
                ps = fmaf(vj, vj, ps);
                unsigned u = __float_as_uint(vj);
                uh.s[j] = (unsigned short)(u >> 16);
                float h = __uint_as_float(u & 0xFFFF0000u);
                ul.s[j] = (unsigned short)(__float_as_uint(vj - h) >> 16);
            }
            if (p) pb += ps; else pa += ps;
            unsigned short* dh = (p ? Bh : Ah) + sn*32 + sch*8;
            unsigned short* dl = (p ? Bl : Al) + sn*32 + sch*8;
            *(bfrag8*)dh = uh.v8;
            *(bfrag8*)dl = ul.v8;
        }
        __syncthreads();
        bfrag8 bh4[4], bl4[4];
        #pragma unroll
        for (int tj = 0; tj < 4; ++tj) {
            int col = C0 + tj*16 + c0;
            bh4[tj] = *(const bfrag8*)(Bh + col*32 + q*8);
            bl4[tj] = *(const bfrag8*)(Bl + col*32 + q*8);
        }
        #pragma unroll
        for (int ti = 0; ti < 4; ++ti) {
            int row = R0 + ti*16 + c0;
            bfrag8 ah = *(const bfrag8*)(Ah + row*32 + q*8);
            bfrag8 al = *(const bfrag8*)(Al + row*32 + q*8);
            #pragma unroll
            for (int tj = 0; tj < 4; ++tj) {
                acc[ti][tj] = __builtin_amdgcn_mfma_f32_16x16x32_bf16(ah, bh4[tj], acc[ti][tj], 0, 0, 0);
                acc[ti][tj] = __builtin_amdgcn_mfma_f32_16x16x32_bf16(ah, bl4[tj], acc[ti][tj], 0, 0, 0);
                acc[ti][tj] = __builtin_amdgcn_mfma_f32_16x16x32_bf16(al, bh4[tj], acc[ti][tj], 0, 0, 0);
            }
        }
    }
    __syncthreads();   // GEMM frag reads done; LDS reused for Sinkhorn

    // point norms: quad-reduce (4 threads per row, lane-adjacent)
    pa += __shfl_xor(pa, 1, 64); pa += __shfl_xor(pa, 2, 64);
    pb += __shfl_xor(pb, 1, 64); pb += __shfl_xor(pb, 2, 64);
    if (sch == 0) { na_s[sn] = pa; nb_s[sn] = pb; }
    if (t < 256) g_l[t] = 0.f;
    if (t < 4) { wredG[t] = 0.f; wredF[t] = 8.f; }   // MS0 = 8 bounds iter-0 z
    __syncthreads();

    // C/D layout (16x16x32): row = R0 + ti*16 + q*4 + r, col = C0 + tj*16 + c0
    facc4 E[4][4];                        // first Ceps2, then 2^(rm - Ceps2)
    {
        float nbv[4];
        #pragma unroll
        for (int tj = 0; tj < 4; ++tj) nbv[tj] = nb_s[C0 + tj*16 + c0];
        #pragma unroll
        for (int ti = 0; ti < 4; ++ti) {
            facc4 nav = *(const facc4*)&na_s[R0 + ti*16 + q*4];
            #pragma unroll
            for (int tj = 0; tj < 4; ++tj) {
                #pragma unroll
                for (int r = 0; r < 4; ++r) {
                    float d2 = fmaxf(nav[r] + nbv[tj] - 2.f*acc[ti][tj][r], 0.f);
                    E[ti][tj][r] = KSC * sqrtf(d2 + 1e-12f);
                }
            }
        }
    }

    // tournament target indices (verified in R2)
    const int istar = ((c0&1)<<3) | ((c0&2)<<1) | ((c0&4)>>1) | ((c0&8)>>3);
    const int rowstar = R0 + (istar>>2)*16 + q*4 + (istar&3);
    const int tjstar = ((q&1)<<1) | (q>>1);
    const int colstar = C0 + tjstar*16 + c0;

    // ---- row mins of Ceps2 ----
    {
        float v16[16];
        #pragma unroll
        for (int ti = 0; ti < 4; ++ti)
            #pragma unroll
            for (int r = 0; r < 4; ++r)
                v16[ti*4+r] = fminf(fminf(E[ti][0][r], E[ti][1][r]),
                                    fminf(E[ti][2][r], E[ti][3][r]));
        #pragma unroll
        for (int p = 0; p < 4; ++p) {
            const int m = 1 << p, hsz = 8 >> p;
            const bool hi = (c0 >> p) & 1;
            #pragma unroll
            for (int j = 0; j < hsz; ++j) {
                float mine = hi ? v16[j+hsz] : v16[j];
                float send = hi ? v16[j] : v16[j+hsz];
                v16[j] = fminf(mine, __shfl_xor(send, m, 64));
            }
        }
        rowred[wc*256 + rowstar] = v16[0];
    }
    __syncthreads();
    if (t < 256)
        rm_l[t] = fminf(fminf(rowred[t], rowred[256+t]), fminf(rowred[512+t], rowred[768+t]));
    __syncthreads();

    // E := 2^(rm_r - Ceps2)
    #pragma unroll
    for (int ti = 0; ti < 4; ++ti) {
        facc4 rmv = *(const facc4*)&rm_l[R0 + ti*16 + q*4];
        #pragma unroll
        for (int tj = 0; tj < 4; ++tj)
            #pragma unroll
            for (int r = 0; r < 4; ++r)
                E[ti][tj][r] = EXP2F(rmv[r] - E[ti][tj][r]);
    }

    // ---- 6 Sinkhorn iterations ----
    // Shifts are exact renormalizers; MS (z-shift) is the PREVIOUS iteration's
    // max-z (stale by one iteration, init 8) so phase B precomputes
    // q_l = 2^(z - MS) and phase C needs no exp2 at all.
    #pragma unroll 1
    for (int it = 0; it < 6; ++it) {
        float Gmax = fmaxf(fmaxf(wredG[0], wredG[1]), fmaxf(wredG[2], wredG[3]));
        float MS   = fmaxf(fmaxf(wredF[0], wredF[1]), fmaxf(wredF[2], wredF[3]));
        // phase A: row sums  S_r = sum_c E * 2^(G_c - Gmax)
        float P4[4];
        #pragma unroll
        for (int tj = 0; tj < 4; ++tj) P4[tj] = EXP2F(g_l[C0 + tj*16 + c0] - Gmax);
        float v16[16];
        #pragma unroll
        for (int ti = 0; ti < 4; ++ti)
            #pragma unroll
            for (int r = 0; r < 4; ++r) {
                float s = 0.f;
                #pragma unroll
                for (int tj = 0; tj < 4; ++tj) s = fmaf(E[ti][tj][r], P4[tj], s);
                v16[ti*4+r] = s;
            }
        #pragma unroll
        for (int p = 0; p < 4; ++p) {
            const int m = 1 << p, hsz = 8 >> p;
            const bool hi = (c0 >> p) & 1;
            #pragma unroll
            for (int j = 0; j < hsz; ++j) {
                float mine = hi ? v16[j+hsz] : v16[j];
                float send = hi ? v16[j] : v16[j+hsz];
                v16[j] = mine + __shfl_xor(send, m, 64);
            }
        }
        rowred[wc*256 + rowstar] = v16[0];
        __syncthreads();
        // phase B: z_r = 8 - Gmax - log2(S_r); q_l = 2^(z - MS); wave-max z -> wredF
        if (t < 256) {
            float s = rowred[t] + rowred[256+t] + rowred[512+t] + rowred[768+t];
            float z = 8.f - Gmax - LOG2F(s);
            z_l[t] = z;
            q_l[t] = EXP2F(z - MS);
            float m = z;
            #pragma unroll
            for (int o = 1; o < 64; o <<= 1) m = fmaxf(m, __shfl_xor(m, o, 64));
            if ((t & 63) == 0) wredF[t >> 6] = m;
        }
        __syncthreads();
        // phase C: col sums  S_c = sum_r E * q_r  (q precomputed, no exp2)
        float Q[16];
        #pragma unroll
        for (int ti = 0; ti < 4; ++ti) {
            facc4 qv = *(const facc4*)&q_l[R0 + ti*16 + q*4];
            #pragma unroll
            for (int r = 0; r < 4; ++r) Q[ti*4+r] = qv[r];
        }
        float w4[4];
        #pragma unroll
        for (int tj = 0; tj < 4; ++tj) {
            float s = 0.f;
            #pragma unroll
            for (int ti = 0; ti < 4; ++ti)
                #pragma unroll
                for (int r = 0; r < 4; ++r) s = fmaf(E[ti][tj][r], Q[ti*4+r], s);
            w4[tj] = s;
        }
        #pragma unroll
        for (int p = 0; p < 2; ++p) {
            const int m = 16 << p, hsz = 2 >> p;
            const bool hi = (q >> p) & 1;
            #pragma unroll
            for (int j = 0; j < hsz; ++j) {
                float mine = hi ? w4[j+hsz] : w4[j];
                float send = hi ? w4[j] : w4[j+hsz];
                w4[j] = mine + __shfl_xor(send, m, 64);
            }
        }
        colred[wr*256 + colstar] = w4[0];
        __syncthreads();
        // phase D: G_c = 8 - MS - log2(S_c); wave-max -> wredG
        if (t < 256) {
            float s = colred[t] + colred[256+t] + colred[512+t] + colred[768+t];
            float G = 8.f - MS - LOG2F(s);
            g_l[t] = G;
            float m = G;
            #pragma unroll
            for (int o = 1; o < 64; o <<= 1) m = fmaxf(m, __shfl_xor(m, o, 64));
            if ((t & 63) == 0) wredG[t >> 6] = m;
        }
        __syncthreads();
    }

    // ---- D = sum(T*C): T = 2^(z_r-8)*2^(G_c-8)*E, C-weight = rm_r - log2 E ----
    {
        float gc[4];
        #pragma unroll
        for (int tj = 0; tj < 4; ++tj) gc[tj] = EXP2F(g_l[C0 + tj*16 + c0] - 8.f);
        float d = 0.f;
        #pragma unroll
        for (int ti = 0; ti < 4; ++ti) {
            facc4 zv = *(const facc4*)&z_l[R0 + ti*16 + q*4];
            facc4 rmv = *(const facc4*)&rm_l[R0 + ti*16 + q*4];
            float fr[4];
            #pragma unroll
            for (int r = 0; r < 4; ++r) fr[r] = EXP2F(zv[r] - 8.f);
            #pragma unroll
            for (int tj = 0; tj < 4; ++tj) {
                #pragma unroll
                for (int r = 0; r < 4; ++r) {
                    float e = fmaxf(E[ti][tj][r], 1e-45f);
                    float lE = LOG2F(e);
                    d = fmaf(e * (fr[r] * gc[tj]), rmv[r] - lE, d);
                }
            }
        }
        d *= C2E;
        #pragma unroll
        for (int o = 1; o < 64; o <<= 1) d += __shfl_xor(d, o, 64);
        if ((t & 63) == 0) wredD[w] = d;
        __syncthreads();
        if (t == 0) {
            float s = 0.f;
            #pragma unroll
            for (int i = 0; i < 16; ++i) s += wredD[i];
            Dmat[a*B_SZ + b] = s;
            Dmat[b*B_SZ + a] = s;
        }
    }
}

// ================= Launch 2: final triplet scan + scalar outputs (1 block) =================
__global__ __launch_bounds__(256) void k_fin(const int* __restrict__ label,
        const float* __restrict__ dists, const float* __restrict__ Dmat,
        float* __restrict__ out) {
    const int t = threadIdx.x;
    __shared__ float ds[576], Dm[576];
    __shared__ int lab[B_SZ];
    __shared__ float wls[4]; __shared__ int wnp[4], wot[4];
    for (int i = t; i < 576; i += 256) { ds[i] = dists[i]; Dm[i] = Dmat[i]; }
    if (t < B_SZ) lab[t] = label[t];
    __syncthreads();
    int np = 0, ot = 0; float wsum = 0.f;
    for (int idx = t; idx < 24*24*24; idx += 256) {
        int a2 = idx / 576;
        int rest = idx - a2*576;
        int p2 = rest / 24;
        int n2 = rest - p2*24;
        int la = lab[a2];
        if (la == lab[p2] && la != lab[n2]) {
            float diff = ds[a2*24 + n2] - ds[a2*24 + p2];
            if (diff > 0.f) {
                ++np;
                float dd = Dm[a2*24 + p2] - Dm[a2*24 + n2];
                if (dd > 0.f) { ++ot; wsum += dd; }
            }
        }
    }
    #pragma unroll
    for (int o = 1; o < 64; o <<= 1) {
        np += __shfl_xor(np, o, 64);
        ot += __shfl_xor(ot, o, 64);
        wsum += __shfl_xor(wsum, o, 64);
    }
    int w = t >> 6;
    if ((t & 63) == 0) { wnp[w] = np; wot[w] = ot; wls[w] = wsum; }
    __syncthreads();
    if (t == 0) {
        int tnp = wnp[0]+wnp[1]+wnp[2]+wnp[3];
        int tot = wot[0]+wot[1]+wot[2]+wot[3];
        float tws = wls[0]+wls[1]+wls[2]+wls[3];
        int den = tot > 1 ? tot : 1;
        float wl = (tws > 0.f) ? tws / (float)den : 0.f;
        out[240000] = wl;
        out[480001] = (float)tnp;
        out[480002] = (float)tot;
    }
}

extern "C" void kernel_launch(void* const* d_in, const int* in_sizes, int n_in,
                              void* d_out, int out_size, void* d_ws, size_t ws_size,
                              hipStream_t stream) {
    (void)in_sizes; (void)n_in; (void)out_size; (void)ws_size;
    const float* emb  = (const float*)d_in[0];
    const float* conv = (const float*)d_in[1];
    const float* kern = (const float*)d_in[2];
    const int*   lab  = (const int*)d_in[3];
    float* out = (float*)d_out;
    float* ws  = (float*)d_ws;
    float* dists = ws;            // 576 floats
    float* Dmat  = ws + 576;      // 576 floats

    k_fused<<<NPAIR + NARC + NGRAM, 1024, 0, stream>>>(emb, conv, kern, lab, dists, Dmat, out);
    k_fin<<<1, 256, 0, stream>>>(lab, dists, Dmat, out);
}

// Round 5
// 198.362 us; speedup vs baseline: 1.2848x; 1.2539x over previous
//
#include <hip/hip_runtime.h>
#include <math.h>

#define B_SZ 24
#define D_EMBD 512
#define N_CLS 10000
#define CC 256
#define HH 196

#define NPAIR 276
#define NARC 40
#define NGRAM 36

#define S_SCALE 64.0f
#define COS_M 0.9004471023526769f
#define SIN_M 0.43496553411123023f
#define TH_C (-0.9004471023526769f)
#define MM_C 0.19573449035005357f
// base-2 scaled Sinkhorn units: Ceps2 = C * log2(e)/eps
#define KSC 14.4269504088896f          /* 10*log2(e) */
#define C2E 0.0693147180559945f        /* eps*ln2 */

typedef short bfrag8 __attribute__((ext_vector_type(8)));
typedef float facc4 __attribute__((ext_vector_type(4)));

#if __has_builtin(__builtin_amdgcn_exp2f)
#define EXP2F(x) __builtin_amdgcn_exp2f(x)
#else
#define EXP2F(x) exp2f(x)
#endif
#if __has_builtin(__builtin_amdgcn_logf)
#define LOG2F(x) __builtin_amdgcn_logf(x)
#else
#define LOG2F(x) __log2f(x)
#endif

__device__ inline unsigned short f2bf_rne(float x) {
    union { float f; unsigned u; } cv; cv.f = x;
    unsigned r = cv.u + 0x7FFFu + ((cv.u >> 16) & 1u);
    return (unsigned short)(r >> 16);
}
__device__ inline float bf2f(unsigned short h) {
    union { unsigned u; float f; } cv; cv.u = ((unsigned)h) << 16; return cv.f;
}

// ================= Launch 1: fused pairs (Sinkhorn) + arcface + emb gram =================
// blocks 0..275          : one (a<b) Sinkhorn pair each (16 waves, 4x4 wave grid)
// blocks 276..315 (40)   : arcface, 256 cols each, kc=t&3 k-quarter per thread
// blocks 316..351 (36)   : 24x24 emb-cosine gram, one pair per wave; first zeros Dmat diag
__global__ __launch_bounds__(1024) void k_fused(const float* __restrict__ emb,
        const float* __restrict__ conv, const float* __restrict__ kern,
        const int* __restrict__ label, float* __restrict__ dists,
        float* __restrict__ Dmat, float* __restrict__ out) {
    const int t = threadIdx.x;
    const int bid = blockIdx.x;

    __shared__ __align__(16) char smem[65536];

    if (bid >= NPAIR) {
        const int sb = bid - NPAIR;
        if (sb >= NARC) {
            // ---- emb gram path (no barriers, no LDS) ----
            const int gid = sb - NARC;
            int l = t & 63, w16 = t >> 6;
            if (gid == 0 && t < B_SZ) Dmat[t * B_SZ + t] = 0.f;
            int pid = gid * 16 + w16;
            if (pid >= B_SZ * B_SZ) return;
            int i = pid / B_SZ, j = pid - (pid / B_SZ) * B_SZ;
            float sij = 0.f, sii = 0.f, sjj = 0.f;
            #pragma unroll
            for (int u = 0; u < 8; ++u) {
                float vi = emb[i*D_EMBD + u*64 + l];
                float vj = emb[j*D_EMBD + u*64 + l];
                sij = fmaf(vi, vj, sij); sii = fmaf(vi, vi, sii); sjj = fmaf(vj, vj, sjj);
            }
            #pragma unroll
            for (int o = 1; o < 64; o <<= 1) {
                sij += __shfl_xor(sij, o, 64);
                sii += __shfl_xor(sii, o, 64);
                sjj += __shfl_xor(sjj, o, 64);
            }
            if (l == 0) dists[pid] = sij * rsqrtf(sii * sjj);
            return;
        }

        // ---- arcface path: 256 cols/block, self-normalizing, reg-only chunk reduce ----
        float* es = (float*)smem;                 // 12288 floats (48 KB)
        float* inv_s = es + B_SZ * D_EMBD;        // 24
        int* lab_s = (int*)(inv_s + B_SZ);        // 24

        {
            const float4* s4 = (const float4*)emb;
            float4* d4 = (float4*)es;
            #pragma unroll
            for (int i = 0; i < 3; ++i) d4[i*1024 + t] = s4[i*1024 + t];
        }
        if (t < B_SZ) lab_s[t] = label[t];
        __syncthreads();
        {   // row norms of emb (16 waves)
            int l = t & 63, w = t >> 6;
            for (int r = w; r < B_SZ; r += 16) {
                float s = 0.f;
                #pragma unroll
                for (int u = 0; u < 8; ++u) { float v = es[r*D_EMBD + u*64 + l]; s = fmaf(v, v, s); }
                #pragma unroll
                for (int o = 1; o < 64; o <<= 1) s += __shfl_xor(s, o, 64);
                if (l == 0) inv_s[r] = rsqrtf(s);
            }
        }
        __syncthreads();

        const int cc = t >> 2, kc = t & 3;        // 256 cols, 4 k-quarters of 128
        const int col = sb * 256 + cc;
        const int cL = col < N_CLS ? col : N_CLS - 1;
        float acc[B_SZ];
        #pragma unroll
        for (int r = 0; r < B_SZ; ++r) acc[r] = 0.f;
        float cn = 0.f;
        const int kb0 = kc << 7;
        for (int u = 0; u < 32; ++u) {
            // per-kc rotation of the k-walk keeps the 4 kc-groups' broadcast
            // float4 LDS reads on disjoint banks
            const int um = (u + kc) & 31;
            const int kb = kb0 + (um << 2);
            float kv0 = kern[(kb+0)*N_CLS + cL];
            float kv1 = kern[(kb+1)*N_CLS + cL];
            float kv2 = kern[(kb+2)*N_CLS + cL];
            float kv3 = kern[(kb+3)*N_CLS + cL];
            cn = fmaf(kv0,kv0,cn); cn = fmaf(kv1,kv1,cn);
            cn = fmaf(kv2,kv2,cn); cn = fmaf(kv3,kv3,cn);
            #pragma unroll
            for (int r = 0; r < B_SZ; ++r) {
                const float4 e = *(const float4*)&es[r*D_EMBD + kb];
                acc[r] = fmaf(e.x, kv0, acc[r]);
                acc[r] = fmaf(e.y, kv1, acc[r]);
                acc[r] = fmaf(e.z, kv2, acc[r]);
                acc[r] = fmaf(e.w, kv3, acc[r]);
            }
        }
        cn += __shfl_xor(cn, 1, 64); cn += __shfl_xor(cn, 2, 64);
        #pragma unroll
        for (int r = 0; r < B_SZ; ++r) {
            acc[r] += __shfl_xor(acc[r], 1, 64);
            acc[r] += __shfl_xor(acc[r], 2, 64);
        }
        if (kc == 0 && col < N_CLS) {
            const float invk = rsqrtf(cn);
            #pragma unroll
            for (int r = 0; r < B_SZ; ++r) {
                float cosv = fminf(fmaxf(acc[r] * inv_s[r] * invk, -1.f), 1.f);
                float oc = cosv * S_SCALE;
                float af = oc;
                if (lab_s[r] == col) {
                    float tl = cosv;
                    float sint = sqrtf(fmaxf(1.f - tl*tl, 0.f));
                    float ctm = tl*COS_M - sint*SIN_M;
                    float ftl = (tl > TH_C) ? ctm : (tl - MM_C);
                    af = ftl * S_SCALE;
                }
                out[r*N_CLS + col] = af;
                out[240001 + r*N_CLS + col] = oc;
            }
        }
        return;
    }

    // ======================= Sinkhorn pair path =======================
    // GEMM overlay: 4 staging buffers [256 rows][32 k] bf16 (16 KB each)
    unsigned short* Ah = (unsigned short*)smem;
    unsigned short* Al = Ah + 8192;
    unsigned short* Bh = Al + 8192;
    unsigned short* Bl = Bh + 8192;
    // Sinkhorn overlay (used strictly after GEMM's last fragment-read barrier)
    float* rowred = (float*)smem;        // [4][256]
    float* colred = rowred + 1024;       // [4][256]
    float* rm_l   = colred + 1024;       // [256]
    float* z_l    = rm_l + 256;          // [256]
    float* g_l    = z_l + 256;           // [256]
    float* na_s   = g_l + 256;           // [256]
    float* nb_s   = na_s + 256;          // [256]
    float* wredF  = nb_s + 256;          // [4]
    float* wredG  = wredF + 4;           // [4]
    float* wredD  = wredG + 4;           // [16]

    const int w = t >> 6;
    const int wr = w >> 2, wc = w & 3;
    const int q = (t >> 4) & 3, c0 = t & 15;
    const int R0 = wr * 64, C0 = wc * 64;

    // pair index -> (a, b), a < b
    int rem = bid, a = 0;
    while (rem >= 23 - a) { rem -= 23 - a; ++a; }
    int b = a + 1 + rem;
    const float* xa = conv + a*CC*HH;
    const float* xb = conv + b*CC*HH;

    const int sn = t >> 2;               // staging row 0..255
    const int sch = t & 3;               // staging 8-k chunk

    facc4 acc[4][4];
    #pragma unroll
    for (int i = 0; i < 4; ++i)
        #pragma unroll
        for (int j = 0; j < 4; ++j) acc[i][j] = (facc4){0.f, 0.f, 0.f, 0.f};

    float pa = 0.f, pb = 0.f;            // inline point-norm partials

    // ---- GEMM: G = Xa . Xb^T, K padded 196 -> 224, 7 K-steps of 32 ----
    for (int ks = 0; ks < 224; ks += 32) {
        __syncthreads();
        #pragma unroll
        for (int p = 0; p < 2; ++p) {
            int k0 = ks + sch*8;
            const float* src = (p ? xb : xa) + sn*HH + k0;
            float v[8];
            if (k0 + 8 <= HH) {
                const float4* s4 = (const float4*)src;
                float4 u0 = s4[0], u1 = s4[1];
                v[0]=u0.x; v[1]=u0.y; v[2]=u0.z; v[3]=u0.w;
                v[4]=u1.x; v[5]=u1.y; v[6]=u1.z; v[7]=u1.w;
            } else {
                #pragma unroll
                for (int j = 0; j < 8; ++j) v[j] = (k0 + j < HH) ? src[j] : 0.f;
            }
            float ps = 0.f;
            union { unsigned short s[8]; bfrag8 v8; } uh, ul;
            #pragma unroll
            for (int j = 0; j < 8; ++j) {
                ps = fmaf(v[j], v[j], ps);
                unsigned short hb = f2bf_rne(v[j]);
                uh.s[j] = hb;
                ul.s[j] = f2bf_rne(v[j] - bf2f(hb));
            }
            if (p) pb += ps; else pa += ps;
            unsigned short* dh = (p ? Bh : Ah) + sn*32 + sch*8;
            unsigned short* dl = (p ? Bl : Al) + sn*32 + sch*8;
            *(bfrag8*)dh = uh.v8;
            *(bfrag8*)dl = ul.v8;
        }
        __syncthreads();
        bfrag8 bh4[4], bl4[4];
        #pragma unroll
        for (int tj = 0; tj < 4; ++tj) {
            int col = C0 + tj*16 + c0;
            bh4[tj] = *(const bfrag8*)(Bh + col*32 + q*8);
            bl4[tj] = *(const bfrag8*)(Bl + col*32 + q*8);
        }
        #pragma unroll
        for (int ti = 0; ti < 4; ++ti) {
            int row = R0 + ti*16 + c0;
            bfrag8 ah = *(const bfrag8*)(Ah + row*32 + q*8);
            bfrag8 al = *(const bfrag8*)(Al + row*32 + q*8);
            #pragma unroll
            for (int tj = 0; tj < 4; ++tj) {
                acc[ti][tj] = __builtin_amdgcn_mfma_f32_16x16x32_bf16(ah, bh4[tj], acc[ti][tj], 0, 0, 0);
                acc[ti][tj] = __builtin_amdgcn_mfma_f32_16x16x32_bf16(ah, bl4[tj], acc[ti][tj], 0, 0, 0);
                acc[ti][tj] = __builtin_amdgcn_mfma_f32_16x16x32_bf16(al, bh4[tj], acc[ti][tj], 0, 0, 0);
            }
        }
    }
    __syncthreads();   // GEMM frag reads done; LDS reused for Sinkhorn

    // point norms: quad-reduce (4 threads per row, lane-adjacent)
    pa += __shfl_xor(pa, 1, 64); pa += __shfl_xor(pa, 2, 64);
    pb += __shfl_xor(pb, 1, 64); pb += __shfl_xor(pb, 2, 64);
    if (sch == 0) { na_s[sn] = pa; nb_s[sn] = pb; }
    if (t < 256) g_l[t] = 0.f;
    if (t < 4) wredG[t] = 0.f;
    __syncthreads();

    // C/D layout (16x16x32): row = R0 + ti*16 + q*4 + r, col = C0 + tj*16 + c0
    facc4 E[4][4];                        // first Ceps2, then 2^(rm - Ceps2)
    {
        float nbv[4];
        #pragma unroll
        for (int tj = 0; tj < 4; ++tj) nbv[tj] = nb_s[C0 + tj*16 + c0];
        #pragma unroll
        for (int ti = 0; ti < 4; ++ti) {
            facc4 nav = *(const facc4*)&na_s[R0 + ti*16 + q*4];
            #pragma unroll
            for (int tj = 0; tj < 4; ++tj) {
                #pragma unroll
                for (int r = 0; r < 4; ++r) {
                    float d2 = fmaxf(nav[r] + nbv[tj] - 2.f*acc[ti][tj][r], 0.f);
                    E[ti][tj][r] = KSC * sqrtf(d2 + 1e-12f);
                }
            }
        }
    }

    // tournament target indices (verified in R2)
    const int istar = ((c0&1)<<3) | ((c0&2)<<1) | ((c0&4)>>1) | ((c0&8)>>3);
    const int rowstar = R0 + (istar>>2)*16 + q*4 + (istar&3);
    const int tjstar = ((q&1)<<1) | (q>>1);
    const int colstar = C0 + tjstar*16 + c0;

    // ---- row mins of Ceps2 ----
    {
        float v16[16];
        #pragma unroll
        for (int ti = 0; ti < 4; ++ti)
            #pragma unroll
            for (int r = 0; r < 4; ++r)
                v16[ti*4+r] = fminf(fminf(E[ti][0][r], E[ti][1][r]),
                                    fminf(E[ti][2][r], E[ti][3][r]));
        #pragma unroll
        for (int p = 0; p < 4; ++p) {
            const int m = 1 << p, hsz = 8 >> p;
            const bool hi = (c0 >> p) & 1;
            #pragma unroll
            for (int j = 0; j < hsz; ++j) {
                float mine = hi ? v16[j+hsz] : v16[j];
                float send = hi ? v16[j] : v16[j+hsz];
                v16[j] = fminf(mine, __shfl_xor(send, m, 64));
            }
        }
        rowred[wc*256 + rowstar] = v16[0];
    }
    __syncthreads();
    if (t < 256)
        rm_l[t] = fminf(fminf(rowred[t], rowred[256+t]), fminf(rowred[512+t], rowred[768+t]));
    __syncthreads();

    // E := 2^(rm_r - Ceps2)
    #pragma unroll
    for (int ti = 0; ti < 4; ++ti) {
        facc4 rmv = *(const facc4*)&rm_l[R0 + ti*16 + q*4];
        #pragma unroll
        for (int tj = 0; tj < 4; ++tj)
            #pragma unroll
            for (int r = 0; r < 4; ++r)
                E[ti][tj][r] = EXP2F(rmv[r] - E[ti][tj][r]);
    }

    // ---- 6 Sinkhorn iterations (FMA inner loops) ----
    #pragma unroll 1
    for (int it = 0; it < 6; ++it) {
        // phase A: row sums  S_r = sum_c E * 2^(G_c - Gmax)
        float Gmax = fmaxf(fmaxf(wredG[0], wredG[1]), fmaxf(wredG[2], wredG[3]));
        float P4[4];
        #pragma unroll
        for (int tj = 0; tj < 4; ++tj) P4[tj] = EXP2F(g_l[C0 + tj*16 + c0] - Gmax);
        float v16[16];
        #pragma unroll
        for (int ti = 0; ti < 4; ++ti)
            #pragma unroll
            for (int r = 0; r < 4; ++r) {
                float s = 0.f;
                #pragma unroll
                for (int tj = 0; tj < 4; ++tj) s = fmaf(E[ti][tj][r], P4[tj], s);
                v16[ti*4+r] = s;
            }
        #pragma unroll
        for (int p = 0; p < 4; ++p) {
            const int m = 1 << p, hsz = 8 >> p;
            const bool hi = (c0 >> p) & 1;
            #pragma unroll
            for (int j = 0; j < hsz; ++j) {
                float mine = hi ? v16[j+hsz] : v16[j];
                float send = hi ? v16[j] : v16[j+hsz];
                v16[j] = mine + __shfl_xor(send, m, 64);
            }
        }
        rowred[wc*256 + rowstar] = v16[0];
        __syncthreads();
        // phase B: z_r = F_r - rm_r = 8 - Gmax - log2(S_r); wave-max -> wredF
        if (t < 256) {
            float s = rowred[t] + rowred[256+t] + rowred[512+t] + rowred[768+t];
            float z = 8.f - Gmax - LOG2F(s);
            z_l[t] = z;
            float m = z;
            #pragma unroll
            for (int o = 1; o < 64; o <<= 1) m = fmaxf(m, __shfl_xor(m, o, 64));
            if ((t & 63) == 0) wredF[t >> 6] = m;
        }
        __syncthreads();
        // phase C: col sums  S_c = sum_r E * 2^(z_r - M)
        float M = fmaxf(fmaxf(wredF[0], wredF[1]), fmaxf(wredF[2], wredF[3]));
        float Q[16];
        #pragma unroll
        for (int ti = 0; ti < 4; ++ti) {
            facc4 zv = *(const facc4*)&z_l[R0 + ti*16 + q*4];
            #pragma unroll
            for (int r = 0; r < 4; ++r) Q[ti*4+r] = EXP2F(zv[r] - M);
        }
        float w4[4];
        #pragma unroll
        for (int tj = 0; tj < 4; ++tj) {
            float s = 0.f;
            #pragma unroll
            for (int ti = 0; ti < 4; ++ti)
                #pragma unroll
                for (int r = 0; r < 4; ++r) s = fmaf(E[ti][tj][r], Q[ti*4+r], s);
            w4[tj] = s;
        }
        #pragma unroll
        for (int p = 0; p < 2; ++p) {
            const int m = 16 << p, hsz = 2 >> p;
            const bool hi = (q >> p) & 1;
            #pragma unroll
            for (int j = 0; j < hsz; ++j) {
                float mine = hi ? w4[j+hsz] : w4[j];
                float send = hi ? w4[j] : w4[j+hsz];
                w4[j] = mine + __shfl_xor(send, m, 64);
            }
        }
        colred[wr*256 + colstar] = w4[0];
        __syncthreads();
        // phase D: G_c = 8 - M - log2(S_c); wave-max -> wredG
        if (t < 256) {
            float s = colred[t] + colred[256+t] + colred[512+t] + colred[768+t];
            float G = 8.f - M - LOG2F(s);
            g_l[t] = G;
            float m = G;
            #pragma unroll
            for (int o = 1; o < 64; o <<= 1) m = fmaxf(m, __shfl_xor(m, o, 64));
            if ((t & 63) == 0) wredG[t >> 6] = m;
        }
        __syncthreads();
    }

    // ---- D = sum(T*C): T = 2^(z_r + G_c - 16 + log2 E), Ceps2 = rm_r - log2 E ----
    {
        float G4[4];
        #pragma unroll
        for (int tj = 0; tj < 4; ++tj) G4[tj] = g_l[C0 + tj*16 + c0] - 16.f;
        float d = 0.f;
        #pragma unroll
        for (int ti = 0; ti < 4; ++ti) {
            facc4 zv = *(const facc4*)&z_l[R0 + ti*16 + q*4];
            facc4 rmv = *(const facc4*)&rm_l[R0 + ti*16 + q*4];
            #pragma unroll
            for (int tj = 0; tj < 4; ++tj) {
                #pragma unroll
                for (int r = 0; r < 4; ++r) {
                    float e = fmaxf(E[ti][tj][r], 1e-45f);
                    float lE = LOG2F(e);
                    float ce = rmv[r] - lE;               // Ceps2
                    d = fmaf(EXP2F(zv[r] + G4[tj] + lE), ce, d);
                }
            }
        }
        d *= C2E;
        #pragma unroll
        for (int o = 1; o < 64; o <<= 1) d += __shfl_xor(d, o, 64);
        if ((t & 63) == 0) wredD[w] = d;
        __syncthreads();
        if (t == 0) {
            float s = 0.f;
            #pragma unroll
            for (int i = 0; i < 16; ++i) s += wredD[i];
            Dmat[a*B_SZ + b] = s;
            Dmat[b*B_SZ + a] = s;
        }
    }
}

// ================= Launch 2: final triplet scan + scalar outputs (1 block) =================
__global__ __launch_bounds__(256) void k_fin(const int* __restrict__ label,
        const float* __restrict__ dists, const float* __restrict__ Dmat,
        float* __restrict__ out) {
    const int t = threadIdx.x;
    __shared__ float ds[576], Dm[576];
    __shared__ int lab[B_SZ];
    __shared__ float wls[4]; __shared__ int wnp[4], wot[4];
    for (int i = t; i < 576; i += 256) { ds[i] = dists[i]; Dm[i] = Dmat[i]; }
    if (t < B_SZ) lab[t] = label[t];
    __syncthreads();
    int np = 0, ot = 0; float wsum = 0.f;
    for (int idx = t; idx < 24*24*24; idx += 256) {
        int a2 = idx / 576;
        int rest = idx - a2*576;
        int p2 = rest / 24;
        int n2 = rest - p2*24;
        int la = lab[a2];
        if (la == lab[p2] && la != lab[n2]) {
            float diff = ds[a2*24 + n2] - ds[a2*24 + p2];
            if (diff > 0.f) {
                ++np;
                float dd = Dm[a2*24 + p2] - Dm[a2*24 + n2];
                if (dd > 0.f) { ++ot; wsum += dd; }
            }
        }
    }
    #pragma unroll
    for (int o = 1; o < 64; o <<= 1) {
        np += __shfl_xor(np, o, 64);
        ot += __shfl_xor(ot, o, 64);
        wsum += __shfl_xor(wsum, o, 64);
    }
    int w = t >> 6;
    if ((t & 63) == 0) { wnp[w] = np; wot[w] = ot; wls[w] = wsum; }
    __syncthreads();
    if (t == 0) {
        int tnp = wnp[0]+wnp[1]+wnp[2]+wnp[3];
        int tot = wot[0]+wot[1]+wot[2]+wot[3];
        float tws = wls[0]+wls[1]+wls[2]+wls[3];
        int den = tot > 1 ? tot : 1;
        float wl = (tws > 0.f) ? tws / (float)den : 0.f;
        out[240000] = wl;
        out[480001] = (float)tnp;
        out[480002] = (float)tot;
    }
}

extern "C" void kernel_launch(void* const* d_in, const int* in_sizes, int n_in,
                              void* d_out, int out_size, void* d_ws, size_t ws_size,
                              hipStream_t stream) {
    (void)in_sizes; (void)n_in; (void)out_size; (void)ws_size;
    const float* emb  = (const float*)d_in[0];
    const float* conv = (const float*)d_in[1];
    const float* kern = (const float*)d_in[2];
    const int*   lab  = (const int*)d_in[3];
    float* out = (float*)d_out;
    float* ws  = (float*)d_ws;
    float* dists = ws;            // 576 floats
    float* Dmat  = ws + 576;      // 576 floats

    k_fused<<<NPAIR + NARC + NGRAM, 1024, 0, stream>>>(emb, conv, kern, lab, dists, Dmat, out);
    k_fin<<<1, 256, 0, stream>>>(lab, dists, Dmat, out);
}

// Round 6
// 192.240 us; speedup vs baseline: 1.3257x; 1.0318x over previous
//
#include <hip/hip_runtime.h>
#include <math.h>

#define B_SZ 24
#define D_EMBD 512
#define N_CLS 10000
#define CC 256
#define HH 196

#define NPAIR 276
#define NARC 40
#define NGRAM 36

#define S_SCALE 64.0f
#define COS_M 0.9004471023526769f
#define SIN_M 0.43496553411123023f
#define TH_C (-0.9004471023526769f)
#define MM_C 0.19573449035005357f
// base-2 scaled Sinkhorn units: Ceps2 = C * log2(e)/eps
#define KSC 14.4269504088896f          /* 10*log2(e) */
#define C2E 0.0693147180559945f        /* eps*ln2 */

typedef short bfrag8 __attribute__((ext_vector_type(8)));
typedef float facc4 __attribute__((ext_vector_type(4)));

#if __has_builtin(__builtin_amdgcn_exp2f)
#define EXP2F(x) __builtin_amdgcn_exp2f(x)
#else
#define EXP2F(x) exp2f(x)
#endif
#if __has_builtin(__builtin_amdgcn_logf)
#define LOG2F(x) __builtin_amdgcn_logf(x)
#else
#define LOG2F(x) __log2f(x)
#endif

__device__ inline unsigned short f2bf_rne(float x) {
    union { float f; unsigned u; } cv; cv.f = x;
    unsigned r = cv.u + 0x7FFFu + ((cv.u >> 16) & 1u);
    return (unsigned short)(r >> 16);
}
__device__ inline float bf2f(unsigned short h) {
    union { unsigned u; float f; } cv; cv.u = ((unsigned)h) << 16; return cv.f;
}

// ================= Launch 1: fused pairs (Sinkhorn) + arcface + emb gram =================
// blocks 0..275          : one (a<b) Sinkhorn pair each (16 waves, 4x4 wave grid)
// blocks 276..315 (40)   : arcface, 256 cols each, kc=t&3 k-quarter per thread
// blocks 316..351 (36)   : 24x24 emb-cosine gram, one pair per wave; first zeros Dmat diag
//
// SPILL TRIPWIRE (R2-R5 post-mortem): pair path sits at the 128 reg/thread
// unified VGPR+AGPR cliff. If WRITE_SIZE jumps from ~1.9 MB to ~155 MB, the
// allocator demoted the 64-float E array to scratch -- revert the last change.
__global__ __launch_bounds__(1024) void k_fused(const float* __restrict__ emb,
        const float* __restrict__ conv, const float* __restrict__ kern,
        const int* __restrict__ label, float* __restrict__ dists,
        float* __restrict__ Dmat, float* __restrict__ out) {
    const int t = threadIdx.x;
    const int bid = blockIdx.x;

    __shared__ __align__(16) char smem[65536];

    if (bid >= NPAIR) {
        const int sb = bid - NPAIR;
        if (sb >= NARC) {
            // ---- emb gram path (no barriers, no LDS) ----
            const int gid = sb - NARC;
            int l = t & 63, w16 = t >> 6;
            if (gid == 0 && t < B_SZ) Dmat[t * B_SZ + t] = 0.f;
            int pid = gid * 16 + w16;
            if (pid >= B_SZ * B_SZ) return;
            int i = pid / B_SZ, j = pid - (pid / B_SZ) * B_SZ;
            float sij = 0.f, sii = 0.f, sjj = 0.f;
            #pragma unroll
            for (int u = 0; u < 8; ++u) {
                float vi = emb[i*D_EMBD + u*64 + l];
                float vj = emb[j*D_EMBD + u*64 + l];
                sij = fmaf(vi, vj, sij); sii = fmaf(vi, vi, sii); sjj = fmaf(vj, vj, sjj);
            }
            #pragma unroll
            for (int o = 1; o < 64; o <<= 1) {
                sij += __shfl_xor(sij, o, 64);
                sii += __shfl_xor(sii, o, 64);
                sjj += __shfl_xor(sjj, o, 64);
            }
            if (l == 0) dists[pid] = sij * rsqrtf(sii * sjj);
            return;
        }

        // ---- arcface path: 256 cols/block, self-normalizing, reg-only chunk reduce ----
        float* es = (float*)smem;                 // 12288 floats (48 KB)
        float* inv_s = es + B_SZ * D_EMBD;        // 24
        int* lab_s = (int*)(inv_s + B_SZ);        // 24

        {
            const float4* s4 = (const float4*)emb;
            float4* d4 = (float4*)es;
            #pragma unroll
            for (int i = 0; i < 3; ++i) d4[i*1024 + t] = s4[i*1024 + t];
        }
        if (t < B_SZ) lab_s[t] = label[t];
        __syncthreads();
        {   // row norms of emb (16 waves)
            int l = t & 63, w = t >> 6;
            for (int r = w; r < B_SZ; r += 16) {
                float s = 0.f;
                #pragma unroll
                for (int u = 0; u < 8; ++u) { float v = es[r*D_EMBD + u*64 + l]; s = fmaf(v, v, s); }
                #pragma unroll
                for (int o = 1; o < 64; o <<= 1) s += __shfl_xor(s, o, 64);
                if (l == 0) inv_s[r] = rsqrtf(s);
            }
        }
        __syncthreads();

        const int cc = t >> 2, kc = t & 3;        // 256 cols, 4 k-quarters of 128
        const int col = sb * 256 + cc;
        const int cL = col < N_CLS ? col : N_CLS - 1;
        float acc[B_SZ];
        #pragma unroll
        for (int r = 0; r < B_SZ; ++r) acc[r] = 0.f;
        float cn = 0.f;
        const int kb0 = kc << 7;
        for (int u = 0; u < 32; ++u) {
            // per-kc rotation of the k-walk keeps the 4 kc-groups' broadcast
            // float4 LDS reads on disjoint banks
            const int um = (u + kc) & 31;
            const int kb = kb0 + (um << 2);
            float kv0 = kern[(kb+0)*N_CLS + cL];
            float kv1 = kern[(kb+1)*N_CLS + cL];
            float kv2 = kern[(kb+2)*N_CLS + cL];
            float kv3 = kern[(kb+3)*N_CLS + cL];
            cn = fmaf(kv0,kv0,cn); cn = fmaf(kv1,kv1,cn);
            cn = fmaf(kv2,kv2,cn); cn = fmaf(kv3,kv3,cn);
            #pragma unroll
            for (int r = 0; r < B_SZ; ++r) {
                const float4 e = *(const float4*)&es[r*D_EMBD + kb];
                acc[r] = fmaf(e.x, kv0, acc[r]);
                acc[r] = fmaf(e.y, kv1, acc[r]);
                acc[r] = fmaf(e.z, kv2, acc[r]);
                acc[r] = fmaf(e.w, kv3, acc[r]);
            }
        }
        cn += __shfl_xor(cn, 1, 64); cn += __shfl_xor(cn, 2, 64);
        #pragma unroll
        for (int r = 0; r < B_SZ; ++r) {
            acc[r] += __shfl_xor(acc[r], 1, 64);
            acc[r] += __shfl_xor(acc[r], 2, 64);
        }
        if (kc == 0 && col < N_CLS) {
            const float invk = rsqrtf(cn);
            #pragma unroll
            for (int r = 0; r < B_SZ; ++r) {
                float cosv = fminf(fmaxf(acc[r] * inv_s[r] * invk, -1.f), 1.f);
                float oc = cosv * S_SCALE;
                float af = oc;
                if (lab_s[r] == col) {
                    float tl = cosv;
                    float sint = sqrtf(fmaxf(1.f - tl*tl, 0.f));
                    float ctm = tl*COS_M - sint*SIN_M;
                    float ftl = (tl > TH_C) ? ctm : (tl - MM_C);
                    af = ftl * S_SCALE;
                }
                out[r*N_CLS + col] = af;
                out[240001 + r*N_CLS + col] = oc;
            }
        }
        return;
    }

    // ======================= Sinkhorn pair path =======================
    // GEMM overlay: 4 staging buffers [256 rows][32 k] bf16 (16 KB each)
    unsigned short* Ah = (unsigned short*)smem;
    unsigned short* Al = Ah + 8192;
    unsigned short* Bh = Al + 8192;
    unsigned short* Bl = Bh + 8192;
    // Sinkhorn overlay (used strictly after GEMM's last fragment-read barrier)
    float* rowred = (float*)smem;        // [4][256]
    float* colred = rowred + 1024;       // [4][256]
    float* rm_l   = colred + 1024;       // [256]
    float* z_l    = rm_l + 256;          // [256]
    float* g_l    = z_l + 256;           // [256]
    float* q_l    = g_l + 256;           // [256]  2^(z - MS), built in phase B
    float* na_s   = q_l + 256;           // [256]
    float* nb_s   = na_s + 256;          // [256]
    float* wredF  = nb_s + 256;          // [4]
    float* wredG  = wredF + 4;           // [4]
    float* wredD  = wredG + 4;           // [16]

    const int w = t >> 6;
    const int wr = w >> 2, wc = w & 3;
    const int q = (t >> 4) & 3, c0 = t & 15;
    const int R0 = wr * 64, C0 = wc * 64;

    // pair index -> (a, b), a < b
    int rem = bid, a = 0;
    while (rem >= 23 - a) { rem -= 23 - a; ++a; }
    int b = a + 1 + rem;
    const float* xa = conv + a*CC*HH;
    const float* xb = conv + b*CC*HH;

    const int sn = t >> 2;               // staging row 0..255
    const int sch = t & 3;               // staging 8-k chunk

    facc4 acc[4][4];
    #pragma unroll
    for (int i = 0; i < 4; ++i)
        #pragma unroll
        for (int j = 0; j < 4; ++j) acc[i][j] = (facc4){0.f, 0.f, 0.f, 0.f};

    float pa = 0.f, pb = 0.f;            // inline point-norm partials

    // ---- GEMM: G = Xa . Xb^T, K padded 196 -> 224, 7 K-steps of 32 ----
    for (int ks = 0; ks < 224; ks += 32) {
        __syncthreads();
        #pragma unroll
        for (int p = 0; p < 2; ++p) {
            int k0 = ks + sch*8;
            const float* src = (p ? xb : xa) + sn*HH + k0;
            float v[8];
            if (k0 + 8 <= HH) {
                const float4* s4 = (const float4*)src;
                float4 u0 = s4[0], u1 = s4[1];
                v[0]=u0.x; v[1]=u0.y; v[2]=u0.z; v[3]=u0.w;
                v[4]=u1.x; v[5]=u1.y; v[6]=u1.z; v[7]=u1.w;
            } else {
                #pragma unroll
                for (int j = 0; j < 8; ++j) v[j] = (k0 + j < HH) ? src[j] : 0.f;
            }
            float ps = 0.f;
            union { unsigned short s[8]; bfrag8 v8; } uh, ul;
            #pragma unroll
            for (int j = 0; j < 8; ++j) {
                ps = fmaf(v[j], v[j], ps);
                unsigned short hb = f2bf_rne(v[j]);
                uh.s[j] = hb;
                ul.s[j] = f2bf_rne(v[j] - bf2f(hb));
            }
            if (p) pb += ps; else pa += ps;
            unsigned short* dh = (p ? Bh : Ah) + sn*32 + sch*8;
            unsigned short* dl = (p ? Bl : Al) + sn*32 + sch*8;
            *(bfrag8*)dh = uh.v8;
            *(bfrag8*)dl = ul.v8;
        }
        __syncthreads();
        bfrag8 bh4[4], bl4[4];
        #pragma unroll
        for (int tj = 0; tj < 4; ++tj) {
            int col = C0 + tj*16 + c0;
            bh4[tj] = *(const bfrag8*)(Bh + col*32 + q*8);
            bl4[tj] = *(const bfrag8*)(Bl + col*32 + q*8);
        }
        #pragma unroll
        for (int ti = 0; ti < 4; ++ti) {
            int row = R0 + ti*16 + c0;
            bfrag8 ah = *(const bfrag8*)(Ah + row*32 + q*8);
            bfrag8 al = *(const bfrag8*)(Al + row*32 + q*8);
            #pragma unroll
            for (int tj = 0; tj < 4; ++tj) {
                acc[ti][tj] = __builtin_amdgcn_mfma_f32_16x16x32_bf16(ah, bh4[tj], acc[ti][tj], 0, 0, 0);
                acc[ti][tj] = __builtin_amdgcn_mfma_f32_16x16x32_bf16(ah, bl4[tj], acc[ti][tj], 0, 0, 0);
                acc[ti][tj] = __builtin_amdgcn_mfma_f32_16x16x32_bf16(al, bh4[tj], acc[ti][tj], 0, 0, 0);
            }
        }
    }
    __syncthreads();   // GEMM frag reads done; LDS reused for Sinkhorn

    // point norms: quad-reduce (4 threads per row, lane-adjacent)
    pa += __shfl_xor(pa, 1, 64); pa += __shfl_xor(pa, 2, 64);
    pb += __shfl_xor(pb, 1, 64); pb += __shfl_xor(pb, 2, 64);
    if (sch == 0) { na_s[sn] = pa; nb_s[sn] = pb; }
    if (t < 256) g_l[t] = 0.f;
    if (t < 4) { wredG[t] = 0.f; wredF[t] = 8.f; }   // MS0 = 8 bounds iter-0 z
    __syncthreads();

    // C/D layout (16x16x32): row = R0 + ti*16 + q*4 + r, col = C0 + tj*16 + c0
    facc4 E[4][4];                        // first Ceps2, then 2^(rm - Ceps2)
    {
        float nbv[4];
        #pragma unroll
        for (int tj = 0; tj < 4; ++tj) nbv[tj] = nb_s[C0 + tj*16 + c0];
        #pragma unroll
        for (int ti = 0; ti < 4; ++ti) {
            facc4 nav = *(const facc4*)&na_s[R0 + ti*16 + q*4];
            #pragma unroll
            for (int tj = 0; tj < 4; ++tj) {
                #pragma unroll
                for (int r = 0; r < 4; ++r) {
                    float d2 = fmaxf(nav[r] + nbv[tj] - 2.f*acc[ti][tj][r], 0.f);
                    E[ti][tj][r] = KSC * sqrtf(d2 + 1e-12f);
                }
            }
        }
    }

    // tournament target indices (verified in R2)
    const int istar = ((c0&1)<<3) | ((c0&2)<<1) | ((c0&4)>>1) | ((c0&8)>>3);
    const int rowstar = R0 + (istar>>2)*16 + q*4 + (istar&3);
    const int tjstar = ((q&1)<<1) | (q>>1);
    const int colstar = C0 + tjstar*16 + c0;

    // ---- row mins of Ceps2 ----
    {
        float v16[16];
        #pragma unroll
        for (int ti = 0; ti < 4; ++ti)
            #pragma unroll
            for (int r = 0; r < 4; ++r)
                v16[ti*4+r] = fminf(fminf(E[ti][0][r], E[ti][1][r]),
                                    fminf(E[ti][2][r], E[ti][3][r]));
        #pragma unroll
        for (int p = 0; p < 4; ++p) {
            const int m = 1 << p, hsz = 8 >> p;
            const bool hi = (c0 >> p) & 1;
            #pragma unroll
            for (int j = 0; j < hsz; ++j) {
                float mine = hi ? v16[j+hsz] : v16[j];
                float send = hi ? v16[j] : v16[j+hsz];
                v16[j] = fminf(mine, __shfl_xor(send, m, 64));
            }
        }
        rowred[wc*256 + rowstar] = v16[0];
    }
    __syncthreads();
    if (t < 256)
        rm_l[t] = fminf(fminf(rowred[t], rowred[256+t]), fminf(rowred[512+t], rowred[768+t]));
    __syncthreads();

    // E := 2^(rm_r - Ceps2)
    #pragma unroll
    for (int ti = 0; ti < 4; ++ti) {
        facc4 rmv = *(const facc4*)&rm_l[R0 + ti*16 + q*4];
        #pragma unroll
        for (int tj = 0; tj < 4; ++tj)
            #pragma unroll
            for (int r = 0; r < 4; ++r)
                E[ti][tj][r] = EXP2F(rmv[r] - E[ti][tj][r]);
    }

    // ---- 6 Sinkhorn iterations ----
    // Shifts are exact renormalizers; MS (z-shift for phase C) is the PREVIOUS
    // iteration's max-z (stale, init 8 which bounds iter-0 z) so phase B can
    // precompute q_l = 2^(z - MS) and phase C needs no exp2 at all.
    #pragma unroll 1
    for (int it = 0; it < 6; ++it) {
        float Gmax = fmaxf(fmaxf(wredG[0], wredG[1]), fmaxf(wredG[2], wredG[3]));
        float MS   = fmaxf(fmaxf(wredF[0], wredF[1]), fmaxf(wredF[2], wredF[3]));
        // phase A: row sums  S_r = sum_c E * 2^(G_c - Gmax)
        float P4[4];
        #pragma unroll
        for (int tj = 0; tj < 4; ++tj) P4[tj] = EXP2F(g_l[C0 + tj*16 + c0] - Gmax);
        float v16[16];
        #pragma unroll
        for (int ti = 0; ti < 4; ++ti)
            #pragma unroll
            for (int r = 0; r < 4; ++r) {
                float s = 0.f;
                #pragma unroll
                for (int tj = 0; tj < 4; ++tj) s = fmaf(E[ti][tj][r], P4[tj], s);
                v16[ti*4+r] = s;
            }
        #pragma unroll
        for (int p = 0; p < 4; ++p) {
            const int m = 1 << p, hsz = 8 >> p;
            const bool hi = (c0 >> p) & 1;
            #pragma unroll
            for (int j = 0; j < hsz; ++j) {
                float mine = hi ? v16[j+hsz] : v16[j];
                float send = hi ? v16[j] : v16[j+hsz];
                v16[j] = mine + __shfl_xor(send, m, 64);
            }
        }
        rowred[wc*256 + rowstar] = v16[0];
        __syncthreads();
        // phase B: z_r = 8 - Gmax - log2(S_r); q_l = 2^(z - MS); wave-max z -> wredF
        if (t < 256) {
            float s = rowred[t] + rowred[256+t] + rowred[512+t] + rowred[768+t];
            float z = 8.f - Gmax - LOG2F(s);
            z_l[t] = z;
            q_l[t] = EXP2F(z - MS);
            float m = z;
            #pragma unroll
            for (int o = 1; o < 64; o <<= 1) m = fmaxf(m, __shfl_xor(m, o, 64));
            if ((t & 63) == 0) wredF[t >> 6] = m;
        }
        __syncthreads();
        // phase C: col sums  S_c = sum_r E * q_r  (q precomputed, no exp2)
        float Q[16];
        #pragma unroll
        for (int ti = 0; ti < 4; ++ti) {
            facc4 qv = *(const facc4*)&q_l[R0 + ti*16 + q*4];
            #pragma unroll
            for (int r = 0; r < 4; ++r) Q[ti*4+r] = qv[r];
        }
        float w4[4];
        #pragma unroll
        for (int tj = 0; tj < 4; ++tj) {
            float s = 0.f;
            #pragma unroll
            for (int ti = 0; ti < 4; ++ti)
                #pragma unroll
                for (int r = 0; r < 4; ++r) s = fmaf(E[ti][tj][r], Q[ti*4+r], s);
            w4[tj] = s;
        }
        #pragma unroll
        for (int p = 0; p < 2; ++p) {
            const int m = 16 << p, hsz = 2 >> p;
            const bool hi = (q >> p) & 1;
            #pragma unroll
            for (int j = 0; j < hsz; ++j) {
                float mine = hi ? w4[j+hsz] : w4[j];
                float send = hi ? w4[j] : w4[j+hsz];
                w4[j] = mine + __shfl_xor(send, m, 64);
            }
        }
        colred[wr*256 + colstar] = w4[0];
        __syncthreads();
        // phase D: G_c = 8 - MS - log2(S_c); wave-max -> wredG
        if (t < 256) {
            float s = colred[t] + colred[256+t] + colred[512+t] + colred[768+t];
            float G = 8.f - MS - LOG2F(s);
            g_l[t] = G;
            float m = G;
            #pragma unroll
            for (int o = 1; o < 64; o <<= 1) m = fmaxf(m, __shfl_xor(m, o, 64));
            if ((t & 63) == 0) wredG[t >> 6] = m;
        }
        __syncthreads();
    }

    // ---- D = sum(T*C): T = 2^(z_r + G_c - 16 + log2 E), Ceps2 = rm_r - log2 E ----
    {
        float G4[4];
        #pragma unroll
        for (int tj = 0; tj < 4; ++tj) G4[tj] = g_l[C0 + tj*16 + c0] - 16.f;
        float d = 0.f;
        #pragma unroll
        for (int ti = 0; ti < 4; ++ti) {
            facc4 zv = *(const facc4*)&z_l[R0 + ti*16 + q*4];
            facc4 rmv = *(const facc4*)&rm_l[R0 + ti*16 + q*4];
            #pragma unroll
            for (int tj = 0; tj < 4; ++tj) {
                #pragma unroll
                for (int r = 0; r < 4; ++r) {
                    float e = fmaxf(E[ti][tj][r], 1e-45f);
                    float lE = LOG2F(e);
                    float ce = rmv[r] - lE;               // Ceps2
                    d = fmaf(EXP2F(zv[r] + G4[tj] + lE), ce, d);
                }
            }
        }
        d *= C2E;
        #pragma unroll
        for (int o = 1; o < 64; o <<= 1) d += __shfl_xor(d, o, 64);
        if ((t & 63) == 0) wredD[w] = d;
        __syncthreads();
        if (t == 0) {
            float s = 0.f;
            #pragma unroll
            for (int i = 0; i < 16; ++i) s += wredD[i];
            Dmat[a*B_SZ + b] = s;
            Dmat[b*B_SZ + a] = s;
        }
    }
}

// ================= Launch 2: final triplet scan + scalar outputs (1 block) =================
__global__ __launch_bounds__(256) void k_fin(const int* __restrict__ label,
        const float* __restrict__ dists, const float* __restrict__ Dmat,
        float* __restrict__ out) {
    const int t = threadIdx.x;
    __shared__ float ds[576], Dm[576];
    __shared__ int lab[B_SZ];
    __shared__ float wls[4]; __shared__ int wnp[4], wot[4];
    for (int i = t; i < 576; i += 256) { ds[i] = dists[i]; Dm[i] = Dmat[i]; }
    if (t < B_SZ) lab[t] = label[t];
    __syncthreads();
    int np = 0, ot = 0; float wsum = 0.f;
    for (int idx = t; idx < 24*24*24; idx += 256) {
        int a2 = idx / 576;
        int rest = idx - a2*576;
        int p2 = rest / 24;
        int n2 = rest - p2*24;
        int la = lab[a2];
        if (la == lab[p2] && la != lab[n2]) {
            float diff = ds[a2*24 + n2] - ds[a2*24 + p2];
            if (diff > 0.f) {
                ++np;
                float dd = Dm[a2*24 + p2] - Dm[a2*24 + n2];
                if (dd > 0.f) { ++ot; wsum += dd; }
            }
        }
    }
    #pragma unroll
    for (int o = 1; o < 64; o <<= 1) {
        np += __shfl_xor(np, o, 64);
        ot += __shfl_xor(ot, o, 64);
        wsum += __shfl_xor(wsum, o, 64);
    }
    int w = t >> 6;
    if ((t & 63) == 0) { wnp[w] = np; wot[w] = ot; wls[w] = wsum; }
    __syncthreads();
    if (t == 0) {
        int tnp = wnp[0]+wnp[1]+wnp[2]+wnp[3];
        int tot = wot[0]+wot[1]+wot[2]+wot[3];
        float tws = wls[0]+wls[1]+wls[2]+wls[3];
        int den = tot > 1 ? tot : 1;
        float wl = (tws > 0.f) ? tws / (float)den : 0.f;
        out[240000] = wl;
        out[480001] = (float)tnp;
        out[480002] = (float)tot;
    }
}

extern "C" void kernel_launch(void* const* d_in, const int* in_sizes, int n_in,
                              void* d_out, int out_size, void* d_ws, size_t ws_size,
                              hipStream_t stream) {
    (void)in_sizes; (void)n_in; (void)out_size; (void)ws_size;
    const float* emb  = (const float*)d_in[0];
    const float* conv = (const float*)d_in[1];
    const float* kern = (const float*)d_in[2];
    const int*   lab  = (const int*)d_in[3];
    float* out = (float*)d_out;
    float* ws  = (float*)d_ws;
    float* dists = ws;            // 576 floats
    float* Dmat  = ws + 576;      // 576 floats

    k_fused<<<NPAIR + NARC + NGRAM, 1024, 0, stream>>>(emb, conv, kern, lab, dists, Dmat, out);
    k_fin<<<1, 256, 0, stream>>>(lab, dists, Dmat, out);
}